// Round 12
// baseline (103.529 us; speedup 1.0000x reference)
//
#include <hip/hip_runtime.h>
#include <hip/hip_bf16.h>

#define BATCH 262144
#define NSITES 64
#define NJ 8                    // j-tiles per wave (128 batch elems/wave)
#define BLOCK_BATCH 512         // batch elems per 256-thread block

typedef __attribute__((ext_vector_type(8))) short short8;
typedef __attribute__((ext_vector_type(4))) float f32x4;
typedef __attribute__((ext_vector_type(2))) float f32x2;

__device__ __forceinline__ unsigned cvt_pk_bf16(float a, float b) {
  unsigned r;
  asm("v_cvt_pk_bf16_f32 %0, %1, %2" : "=v"(r) : "v"(a), "v"(b));
  return r;
}
#define LOH2(r) (__builtin_shufflevector((r), (r), 0, 1))
#define HIH2(r) (__builtin_shufflevector((r), (r), 2, 3))

// slot k = [k4 k3 | k2 k1 k0] -> logical chi = 16*k2 + 4*(k4k3) + (k1k0)
__device__ __forceinline__ int qmap(int k) {
  return (((k >> 2) & 1) << 4) | (((k >> 3) & 3) << 2) | (k & 3);
}

// pack: element idx = ((p*4 + f)*64 + l)*8 + t   (chunk = 16B = 8 bf16)
// f = m*2 + h ; l = g*16 + col ; value = bf16(cores[p][qmap(8g+t)][m][h*16+col] - delta)
__global__ void pack_E(const float* __restrict__ cores, unsigned short* __restrict__ Ep) {
  int idx = blockIdx.x * 256 + threadIdx.x;
  if (idx >= (NSITES - 1) * 2048) return;
  int t = idx & 7;
  int l = (idx >> 3) & 63;
  int f = (idx >> 9) & 3;
  int p = idx >> 11;
  int g = l >> 4, col = l & 15;
  int m = f >> 1, h = f & 1;
  int k = 8 * g + t, c = h * 16 + col;
  int b = qmap(k);
  float val = cores[((p * 32 + b) * 2 + m) * 32 + c] - ((b == c) ? 1.0f : 0.0f);
  __hip_bfloat16 hv = __float2bfloat16(val);
  Ep[idx] = *(unsigned short*)&hv;
}

__device__ __forceinline__ void gll16(const void* g, void* l) {
  __builtin_amdgcn_global_load_lds(
      (const __attribute__((address_space(1))) unsigned*)g,
      (__attribute__((address_space(3))) unsigned*)l, 16, 0, 0);
}

// one j-tile: packed-f32 identity update + bf16 MFMA correction
#define BODYJ(jj, xx0, xx1)                                                     \
  {                                                                             \
    union { short8 s8; unsigned u[4]; } vb;                                     \
    vb.u[0] = cvt_pk_bf16(w2[jj][0][0], w2[jj][0][1]);                          \
    vb.u[1] = cvt_pk_bf16(w2[jj][1][0], w2[jj][1][1]);                          \
    vb.u[2] = cvt_pk_bf16(w2[jj][2][0], w2[jj][2][1]);                          \
    vb.u[3] = cvt_pk_bf16(w2[jj][3][0], w2[jj][3][1]);                          \
    const f32x4 z = {0.f, 0.f, 0.f, 0.f};                                       \
    f32x4 r0lo = __builtin_amdgcn_mfma_f32_16x16x32_bf16(A0, vb.s8, z, 0, 0, 0); \
    f32x4 r0hi = __builtin_amdgcn_mfma_f32_16x16x32_bf16(A1, vb.s8, z, 0, 0, 0); \
    f32x4 r1lo = __builtin_amdgcn_mfma_f32_16x16x32_bf16(A2, vb.s8, z, 0, 0, 0); \
    f32x4 r1hi = __builtin_amdgcn_mfma_f32_16x16x32_bf16(A3, vb.s8, z, 0, 0, 0); \
    const float ss = (xx0) + (xx1);                                             \
    const f32x2 sv = {ss, ss}, x0v = {(xx0), (xx0)}, x1v = {(xx1), (xx1)};      \
    w2[jj][0] = sv * w2[jj][0] + x0v * LOH2(r0lo) + x1v * LOH2(r1lo);           \
    w2[jj][1] = sv * w2[jj][1] + x0v * HIH2(r0lo) + x1v * HIH2(r1lo);           \
    w2[jj][2] = sv * w2[jj][2] + x0v * LOH2(r0hi) + x1v * LOH2(r1hi);           \
    w2[jj][3] = sv * w2[jj][3] + x0v * HIH2(r0hi) + x1v * HIH2(r1hi);           \
  }

__global__ __launch_bounds__(256, 4) void mps_chain_kernel(
    const float* __restrict__ X, const float* __restrict__ core0,
    const float* __restrict__ coreN, const unsigned short* __restrict__ Ep,
    float* __restrict__ out) {
  // 4-slot ring: pair s lives in slot s&3. E = 4KB panel, X = 4KB panel.
  __shared__ __align__(16) char Elds[4][4096];
  __shared__ __align__(16) char Xlds[4][4096];
  const int tid = threadIdx.x;
  const int lane = tid & 63;
  const int wave = tid >> 6;
  const int col = lane & 15;  // batch column within 16-wide tile
  const int g = lane >> 4;    // k-group (slots 8g..8g+7)
  const int abase = blockIdx.x * BLOCK_BATCH + wave * (16 * NJ);
  const char* Epc = (const char*)Ep;
  const char* Xc = (const char*)X;
  const size_t xblock = (size_t)blockIdx.x * (BLOCK_BATCH * 8);

  // ---- v0 = X[0] @ core0 (plain compiler loads, one-time) ----
  float c0[2][8];
#pragma unroll
  for (int m = 0; m < 2; ++m)
#pragma unroll
    for (int t = 0; t < 8; ++t) c0[m][t] = core0[m * 32 + qmap(8 * g + t)];

  f32x2 w2[NJ][4];
#pragma unroll
  for (int jj = 0; jj < NJ; ++jj) {
    const float2 xj = *(const float2*)(X + 2 * (size_t)(abase + jj * 16 + col));
#pragma unroll
    for (int q = 0; q < 4; ++q) {
      w2[jj][q][0] = xj.x * c0[0][2 * q] + xj.y * c0[1][2 * q];
      w2[jj][q][1] = xj.x * c0[0][2 * q + 1] + xj.y * c0[1][2 * q + 1];
    }
  }

  // ---- prologue: stage pairs 1..3 into slots 1..3 (order: E,X per pair) ----
#pragma unroll
  for (int k = 1; k <= 3; ++k) {
    gll16(Epc + (size_t)(k - 1) * 4096 + (size_t)tid * 16,
          &Elds[k][wave * 1024]);
    gll16(Xc + (size_t)k * (BATCH * 8) + xblock + (size_t)tid * 16,
          &Xlds[k][wave * 1024]);
  }
  asm volatile("s_waitcnt vmcnt(4)" ::: "memory");  // pair 1 complete
  __builtin_amdgcn_s_barrier();                     // ... in all waves

  // ---- main chain: counted-vmcnt pipeline, distance 3, never vmcnt(0) ----
  // Invariant entering step s: <=4 outstanding = pairs {s+1, s+2}.
#pragma unroll 1
  for (int s = 1; s < NSITES; ++s) {
    const int rs = s & 3;
    const int ws = (s + 3) & 3;
    const int pk = (s + 3 < NSITES) ? s + 3 : NSITES - 1;  // clamped refetch is benign
    gll16(Epc + (size_t)(pk - 1) * 4096 + (size_t)tid * 16,
          &Elds[ws][wave * 1024]);
    gll16(Xc + (size_t)pk * (BATCH * 8) + xblock + (size_t)tid * 16,
          &Xlds[ws][wave * 1024]);
    // 6 in flight -> wait to 4: completes pair s+1 (staged 2 steps ago).
    asm volatile("s_waitcnt vmcnt(4)" ::: "memory");

    const short8* ep = (const short8*)&Elds[rs][lane * 16];
    const short8 A0 = ep[0], A1 = ep[64], A2 = ep[128], A3 = ep[192];
    // x pairs for this wave's 8 j-tiles (broadcast across g, conflict-free)
    const float* xp = (const float*)&Xlds[rs][wave * 1024 + col * 8];
    float xv0[NJ], xv1[NJ];
#pragma unroll
    for (int jj = 0; jj < NJ; ++jj) {
      xv0[jj] = xp[jj * 32];
      xv1[jj] = xp[jj * 32 + 1];
    }

    BODYJ(0, xv0[0], xv1[0]);
    BODYJ(1, xv0[1], xv1[1]);
    BODYJ(2, xv0[2], xv1[2]);
    BODYJ(3, xv0[3], xv1[3]);
    BODYJ(4, xv0[4], xv1[4]);
    BODYJ(5, xv0[5], xv1[5]);
    BODYJ(6, xv0[6], xv1[6]);
    BODYJ(7, xv0[7], xv1[7]);

    // end-of-step barrier: publishes pair s+1 completion to all waves and
    // protects slot (s+4)&3 == rs from next step's DMA until reads are done.
    __builtin_amdgcn_s_barrier();
  }

  // ---- epilogue: out = |v @ coreN| ----
  float cN[8][2];
#pragma unroll
  for (int t = 0; t < 8; ++t) {
    cN[t][0] = coreN[qmap(8 * g + t) * 2 + 0];
    cN[t][1] = coreN[qmap(8 * g + t) * 2 + 1];
  }
#pragma unroll
  for (int jj = 0; jj < NJ; ++jj) {
    float p0 = 0.f, p1 = 0.f;
#pragma unroll
    for (int t = 0; t < 8; ++t) {
      p0 += w2[jj][t >> 1][t & 1] * cN[t][0];
      p1 += w2[jj][t >> 1][t & 1] * cN[t][1];
    }
    p0 += __shfl_xor(p0, 16);
    p0 += __shfl_xor(p0, 32);
    p1 += __shfl_xor(p1, 16);
    p1 += __shfl_xor(p1, 32);
    if (g == 0) {
      const int a = abase + jj * 16 + col;
      out[2 * a] = fabsf(p0);
      out[2 * a + 1] = fabsf(p1);
    }
  }
}

extern "C" void kernel_launch(void* const* d_in, const int* in_sizes, int n_in,
                              void* d_out, int out_size, void* d_ws, size_t ws_size,
                              hipStream_t stream) {
  const float* X = (const float*)d_in[0];
  const float* core0 = (const float*)d_in[1];
  const float* cores = (const float*)d_in[2];
  const float* coreN = (const float*)d_in[3];
  float* out = (float*)d_out;
  unsigned short* Ep = (unsigned short*)d_ws;  // 258048 bytes

  hipLaunchKernelGGL(pack_E, dim3(((NSITES - 1) * 2048 + 255) / 256), dim3(256), 0, stream,
                     cores, Ep);
  hipLaunchKernelGGL(mps_chain_kernel, dim3(BATCH / BLOCK_BATCH), dim3(256), 0, stream, X,
                     core0, coreN, Ep, out);
}